// Round 11
// baseline (766.407 us; speedup 1.0000x reference)
//
#include <hip/hip_runtime.h>
#include <stdint.h>

#define T_TOK 8192
#define DIM   1024
#define NE    8
#define NH    2816
#define NROWS (T_TOK*2)

typedef __attribute__((ext_vector_type(8))) __bf16 bf16x8;
typedef __attribute__((ext_vector_type(4))) float  f32x4;
typedef __attribute__((ext_vector_type(8))) unsigned short ushort8;

typedef __attribute__((address_space(1))) const unsigned int g_as1;
typedef __attribute__((address_space(3))) unsigned int l_as3;
#define GLL(g, l) __builtin_amdgcn_global_load_lds((g_as1*)(g), (l_as3*)(l), 16, 0, 0)
#define MFMA16(a,b,c) __builtin_amdgcn_mfma_f32_16x16x32_bf16(a,b,c,0,0,0)

__device__ __forceinline__ unsigned short f2bf(float f){
  union { float f; uint32_t u; } v; v.f = f;
  uint32_t r = (v.u + 0x7FFFu + ((v.u >> 16) & 1u)) >> 16;
  return (unsigned short)r;
}

// ---------------- zero+init (fused) ----------------

__global__ void zero_init_k(float4* __restrict__ out, int* counts, int* cursor){
  if (blockIdx.x == 0 && threadIdx.x < NE){ counts[threadIdx.x] = 0; cursor[threadIdx.x] = 0; }
  int i = blockIdx.x*blockDim.x + threadIdx.x;
  const int n4 = T_TOK*DIM/4;
  const float4 z = make_float4(0.f,0.f,0.f,0.f);
  for (; i < n4; i += gridDim.x*blockDim.x) out[i] = z;
}

__global__ void cvt_k(const float* __restrict__ x, unsigned short* __restrict__ xbf){
  int i = blockIdx.x*blockDim.x + threadIdx.x;
  const int total = T_TOK*DIM/8;
  for (; i < total; i += gridDim.x*blockDim.x){
    const float4 a = *(const float4*)(x + (size_t)i*8);
    const float4 b = *(const float4*)(x + (size_t)i*8 + 4);
    ushort4 lo = make_ushort4(f2bf(a.x), f2bf(a.y), f2bf(a.z), f2bf(a.w));
    ushort4 hi = make_ushort4(f2bf(b.x), f2bf(b.y), f2bf(b.z), f2bf(b.w));
    *(ushort4*)(xbf + (size_t)i*8)     = lo;
    *(ushort4*)(xbf + (size_t)i*8 + 4) = hi;
  }
}

// ---------------- fused transpose-convert: f32 [R][C] -> bf16 [C][R] ----------------

__global__ __launch_bounds__(256) void transpA_k(
    const float* __restrict__ w1, const float* __restrict__ w3,
    const float* __restrict__ w2,
    unsigned short* __restrict__ w1t, unsigned short* __restrict__ w3t,
    unsigned short* __restrict__ w2t, int zbase)
{
  __shared__ unsigned short Tl[64*72];
  const int z = zbase + blockIdx.y;
  const int f = blockIdx.x;
  const size_t DS = (size_t)DIM*NH;
  const float* src; unsigned short* dst; int R, C, rt, ct;
  if (z < 16){
    R = DIM; C = NH; rt = f/44; ct = f - rt*44;
    const int e = z & 7;
    src = (z < 8 ? w1 : w3) + (size_t)e*DS;
    dst = (z < 8 ? w1t : w3t) + (size_t)e*DS;
  } else {
    R = NH; C = DIM; rt = f/16; ct = f - rt*16;
    const int e = z - 16;
    src = w2 + (size_t)e*DS;
    dst = w2t + (size_t)e*DS;
  }
  const int r0 = rt*64, c0 = ct*64;
  const int t = threadIdx.x;
  #pragma unroll
  for (int i=0;i<4;i++){
    const int r  = (t>>4) + i*16;
    const int cq = t & 15;
    const float4 v = *(const float4*)(src + (size_t)(r0+r)*C + c0 + cq*4);
    Tl[(cq*4+0)*72 + r] = f2bf(v.x);
    Tl[(cq*4+1)*72 + r] = f2bf(v.y);
    Tl[(cq*4+2)*72 + r] = f2bf(v.z);
    Tl[(cq*4+3)*72 + r] = f2bf(v.w);
  }
  __syncthreads();
  #pragma unroll
  for (int i=0;i<2;i++){
    const int c  = i*32 + (t>>3);
    const int r8 = (t&7)*8;
    const ushort8 v = *(const ushort8*)&Tl[c*72 + r8];
    *(ushort8*)(dst + (size_t)(c0+c)*R + r0 + r8) = v;
  }
}

// ---------------- router (fused with x->bf16 convert) ----------------

__global__ void router_k(const float* __restrict__ x, const float* __restrict__ rw,
                         unsigned short* __restrict__ xbf,
                         int* __restrict__ topk_e, float* __restrict__ topk_w,
                         int* __restrict__ counts){
  const int t = blockIdx.x;
  const int l = threadIdx.x;
  const float* xr = x + (size_t)t * DIM;
  unsigned short* xo = xbf + (size_t)t * DIM;
  float acc[NE];
  #pragma unroll
  for (int e=0;e<NE;e++) acc[e] = 0.f;
  #pragma unroll
  for (int i=0;i<4;i++){
    const int idx = l*4 + i*256;
    const float4 xv = *(const float4*)(xr + idx);
    ushort4 pk = make_ushort4(f2bf(xv.x), f2bf(xv.y), f2bf(xv.z), f2bf(xv.w));
    *(ushort4*)(xo + idx) = pk;
    #pragma unroll
    for (int e=0;e<NE;e++){
      const float4 wv = *(const float4*)(rw + e*DIM + idx);
      acc[e] += xv.x*wv.x + xv.y*wv.y + xv.z*wv.z + xv.w*wv.w;
    }
  }
  #pragma unroll
  for (int e=0;e<NE;e++){
    float v = acc[e];
    #pragma unroll
    for (int off=32; off; off>>=1) v += __shfl_xor(v, off);
    acc[e] = v;
  }
  if (l == 0){
    int e0 = 0; float v0 = acc[0];
    #pragma unroll
    for (int e=1;e<NE;e++) if (acc[e] > v0){ v0 = acc[e]; e0 = e; }
    int e1 = -1; float v1 = -1e30f;
    #pragma unroll
    for (int e=0;e<NE;e++) if (e != e0 && acc[e] > v1){ v1 = acc[e]; e1 = e; }
    float ex = __expf(v1 - v0);
    float s  = 1.f + ex;
    topk_e[t*2]   = e0;  topk_e[t*2+1] = e1;
    topk_w[t*2]   = 1.f/s; topk_w[t*2+1] = ex/s;
    atomicAdd(&counts[e0], 1);
    atomicAdd(&counts[e1], 1);
  }
}

__global__ void prefix_k(const int* __restrict__ counts, int* __restrict__ offs){
  if (threadIdx.x == 0 && blockIdx.x == 0){
    int s = 0;
    for (int e=0;e<NE;e++){ offs[e] = s; s += counts[e]; }
  }
}

__global__ void scatter_k(const int* __restrict__ topk_e, const float* __restrict__ topk_w,
                          const int* __restrict__ offs, int* __restrict__ cursor,
                          int* __restrict__ row_tok, float* __restrict__ row_w){
  int t = blockIdx.x*blockDim.x + threadIdx.x;
  if (t >= T_TOK) return;
  #pragma unroll
  for (int k=0;k<2;k++){
    int e = topk_e[t*2+k];
    int p = atomicAdd(&cursor[e], 1);
    int flat = offs[e] + p;
    row_tok[flat] = t;
    row_w[flat]   = topk_w[t*2+k];
  }
}

// ============ FAST GEMMs ============
// Resource law (r2-r10): <=128 regs/wave AND <=80KB LDS -> 2 blocks/CU of 8 waves,
// plus >=1024 active blocks for backfill. Swizzles verified 0-conflict (r6/r7).

// GEMM1 (round-6 proven): 128x128x2 tile, 8 waves (2x4), BK=32, ring-3, vmcnt(3)
__global__ __launch_bounds__(512,2) void gemm1_p(
    const unsigned short* __restrict__ xbf,
    const unsigned short* __restrict__ w1t, const unsigned short* __restrict__ w3t,
    unsigned short* __restrict__ hbuf,
    const int* __restrict__ row_tok,
    const int* __restrict__ counts, const int* __restrict__ offs)
{
  __shared__ unsigned short As [3][128*32];
  __shared__ unsigned short B1s[3][128*32];
  __shared__ unsigned short B3s[3][128*32];   // 72 KB total

  const int i   = blockIdx.y*64 + blockIdx.x;
  const int lid = (i & 7)*1408 + (i >> 3);
  const int e   = lid / 1408;
  const int rem = lid - e*1408;
  const int h0  = (rem >> 6) * 128;
  const int rb  = rem & 63;

  const int cnt = counts[e];
  const int row0 = rb * 128;
  if (row0 >= cnt) return;
  const int nv   = min(128, cnt - row0);
  const int base = offs[e] + row0;
  const int NK   = DIM/32;

  const int t = threadIdx.x;
  const int r_loc = t >> 2, sct = t & 3;
  const int csw = (sct ^ ((r_loc >> 1) & 3)) * 8;
  const int tok = row_tok[base + min(r_loc, nv-1)];
  const unsigned short* aS  = xbf + (size_t)tok*DIM + csw;
  const unsigned short* b1S = w1t + ((size_t)(e*NH + h0) + r_loc)*DIM + csw;
  const unsigned short* b3S = w3t + ((size_t)(e*NH + h0) + r_loc)*DIM + csw;
  const int lo = t*16;

  const int wid = t >> 6, l = t & 63;
  const int wr = wid >> 2, wc = wid & 3;
  const int lr = l & 15,  lk = l >> 4;
  const int rc = (lk ^ ((lr >> 1) & 3)) * 8;

  f32x4 acc1[4][2], acc3[4][2];
  #pragma unroll
  for (int m=0;m<4;m++)
    #pragma unroll
    for (int n=0;n<2;n++){ acc1[m][n] = (f32x4)0.f; acc3[m][n] = (f32x4)0.f; }

  GLL(aS,    (char*)As[0]+lo); GLL(b1S,    (char*)B1s[0]+lo); GLL(b3S,    (char*)B3s[0]+lo);
  GLL(aS+32, (char*)As[1]+lo); GLL(b1S+32, (char*)B1s[1]+lo); GLL(b3S+32, (char*)B3s[1]+lo);

  for (int kt=0; kt<NK; ++kt){
    if (kt < NK-1) asm volatile("s_waitcnt vmcnt(3)" ::: "memory");
    else           asm volatile("s_waitcnt vmcnt(0)" ::: "memory");
    __builtin_amdgcn_s_barrier();

    if (kt+2 < NK){
      const int kA = (kt+2)*32;
      char* ad  = (char*)As [(kt+2)%3];
      char* b1d = (char*)B1s[(kt+2)%3];
      char* b3d = (char*)B3s[(kt+2)%3];
      GLL(aS+kA, ad+lo); GLL(b1S+kA, b1d+lo); GLL(b3S+kA, b3d+lo);
    }

    const unsigned short* Ab  = As [kt%3];
    const unsigned short* B1b = B1s[kt%3];
    const unsigned short* B3b = B3s[kt%3];

    bf16x8 a[4], b1[2], b3[2];
    #pragma unroll
    for (int m=0;m<4;m++) a[m] = *(const bf16x8*)&Ab[(wr*64 + m*16 + lr)*32 + rc];
    #pragma unroll
    for (int n=0;n<2;n++){
      b1[n] = *(const bf16x8*)&B1b[(wc*32 + n*16 + lr)*32 + rc];
      b3[n] = *(const bf16x8*)&B3b[(wc*32 + n*16 + lr)*32 + rc];
    }
    __builtin_amdgcn_s_setprio(1);
    #pragma unroll
    for (int m=0;m<4;m++)
      #pragma unroll
      for (int n=0;n<2;n++){
        acc1[m][n] = MFMA16(a[m], b1[n], acc1[m][n]);
        acc3[m][n] = MFMA16(a[m], b3[n], acc3[m][n]);
      }
    __builtin_amdgcn_s_setprio(0);
  }

  #pragma unroll
  for (int m=0;m<4;m++){
    #pragma unroll
    for (int i2=0;i2<4;i2++){
      const int r = wr*64 + m*16 + lk*4 + i2;
      if (r < nv){
        const size_t rowbase = (size_t)(base + r) * NH;
        #pragma unroll
        for (int n=0;n<2;n++){
          float z  = acc1[m][n][i2];
          float p3 = acc3[m][n][i2];
          float hv = (z / (1.f + __expf(-z))) * p3;
          hbuf[rowbase + h0 + wc*32 + n*16 + lr] = f2bf(hv);
        }
      }
    }
  }
}

// GEMM2 v2: 128x128 tile, BK=64, ring-2 (64KB LDS), 16 MFMA + 12 reads per barrier.
// acc[4][2]=32 AGPR; drain vmcnt(0) is covered: GLLs for kt+1 issue right after the
// barrier and have the full compute phase (~700cy) to land. 8-chunk swizzle (r7).
__global__ __launch_bounds__(512,2) void gemm2_v(
    const unsigned short* __restrict__ hbuf,
    const unsigned short* __restrict__ w2t,
    float* __restrict__ out,
    const int* __restrict__ row_tok, const float* __restrict__ row_w,
    const int* __restrict__ counts, const int* __restrict__ offs)
{
  __shared__ unsigned short As[2][128*64];   // 32 KB
  __shared__ unsigned short Bs[2][128*64];   // 32 KB -> 64 KB, 2 blocks/CU

  const int i   = blockIdx.y*64 + blockIdx.x;     // grid (64, NE*8)
  const int lid = (i & 7)*512 + (i >> 3);
  const int e   = lid >> 9;
  const int rem = lid & 511;
  const int d0  = (rem >> 6) * 128;
  const int rb  = rem & 63;

  const int cnt = counts[e];
  const int row0 = rb * 128;
  if (row0 >= cnt) return;
  const int nv   = min(128, cnt - row0);
  const int base = offs[e] + row0;
  const int NK   = NH/64;                         // 44

  const int t  = threadIdx.x;
  const int r8 = t >> 3, sl = t & 7;
  const int csw = ((sl ^ (r8 & 7)) << 3);         // swizzled src chunk (shorts)
  const unsigned short* aP0 = hbuf + (size_t)(base + min(r8,      nv-1))*NH + csw;
  const unsigned short* aP1 = hbuf + (size_t)(base + min(r8 + 64, nv-1))*NH + csw;
  const unsigned short* bP0 = w2t + ((size_t)(e*DIM + d0) + r8)*NH + csw;
  const unsigned short* bP1 = bP0 + (size_t)64*NH;
  const int lo0 = t*16, lo1 = 8192 + t*16;

  const int wid = t >> 6, l = t & 63;
  const int wr = wid >> 2, wc = wid & 3;          // 2M x 4N; wave = 64 x 32
  const int lr = l & 15,  lk = l >> 4;

  f32x4 acc[4][2];                                // 32 AGPR
  #pragma unroll
  for (int m=0;m<4;m++)
    #pragma unroll
    for (int n=0;n<2;n++) acc[m][n] = (f32x4)0.f;

  // prologue: tile 0
  GLL(aP0, (char*)As[0]+lo0); GLL(aP1, (char*)As[0]+lo1);
  GLL(bP0, (char*)Bs[0]+lo0); GLL(bP1, (char*)Bs[0]+lo1);

  for (int kt=0; kt<NK; ++kt){
    const int cur = kt & 1;
    asm volatile("s_waitcnt vmcnt(0)" ::: "memory");
    __builtin_amdgcn_s_barrier();

    if (kt+1 < NK){
      const int kof = (kt+1)*64;
      char* ad = (char*)As[cur^1];
      char* bd = (char*)Bs[cur^1];
      GLL(aP0+kof, ad+lo0); GLL(aP1+kof, ad+lo1);
      GLL(bP0+kof, bd+lo0); GLL(bP1+kof, bd+lo1);
    }

    const unsigned short* Ab = As[cur];
    const unsigned short* Bb = Bs[cur];

    bf16x8 a[4][2], b[2][2];
    #pragma unroll
    for (int m=0;m<4;m++){
      const int row = wr*64 + m*16 + lr;
      #pragma unroll
      for (int ks=0;ks<2;ks++){
        const int ck = ks*4 + lk;
        a[m][ks] = *(const bf16x8*)&Ab[row*64 + ((ck ^ (row & 7)) << 3)];
      }
    }
    #pragma unroll
    for (int n=0;n<2;n++){
      const int row = wc*32 + n*16 + lr;
      #pragma unroll
      for (int ks=0;ks<2;ks++){
        const int ck = ks*4 + lk;
        b[n][ks] = *(const bf16x8*)&Bb[row*64 + ((ck ^ (row & 7)) << 3)];
      }
    }
    __builtin_amdgcn_s_setprio(1);
    #pragma unroll
    for (int ks=0;ks<2;ks++)
      #pragma unroll
      for (int m=0;m<4;m++)
        #pragma unroll
        for (int n=0;n<2;n++)
          acc[m][n] = MFMA16(a[m][ks], b[n][ks], acc[m][n]);
    __builtin_amdgcn_s_setprio(0);
  }

  #pragma unroll
  for (int m=0;m<4;m++){
    #pragma unroll
    for (int i2=0;i2<4;i2++){
      const int r = wr*64 + m*16 + lk*4 + i2;
      if (r < nv){
        const int flat = base + r;
        const int tok  = row_tok[flat];
        const float wgt = row_w[flat];
        float* orow = out + (size_t)tok * DIM + d0 + wc*32;
        #pragma unroll
        for (int n=0;n<2;n++)
          atomicAdd(&orow[n*16 + lr], acc[m][n][i2] * wgt);
      }
    }
  }
}

// ============ SLOW FALLBACK (f32 weights, small ws) ============

__global__ __launch_bounds__(256) void gemm1_k(
    const unsigned short* __restrict__ xbf,
    const float* __restrict__ w1, const float* __restrict__ w3,
    unsigned short* __restrict__ hbuf,
    const int* __restrict__ row_tok,
    const int* __restrict__ counts, const int* __restrict__ offs)
{
  __shared__ unsigned short Al [128*32];
  __shared__ unsigned short B1l[128*32];
  __shared__ unsigned short B3l[128*32];
  const int e   = blockIdx.y >> 6;
  const int rb  = blockIdx.y & 63;
  const int cnt = counts[e];
  const int row0 = rb * 128;
  if (row0 >= cnt) return;
  const int nv   = min(128, cnt - row0);
  const int base = offs[e] + row0;
  const int h0   = blockIdx.x * 128;
  const int t  = threadIdx.x;
  const int ar0 = t >> 2;
  const int ac  = t & 3;
  const int tok0 = row_tok[base + min(ar0,      nv-1)];
  const int tok1 = row_tok[base + min(ar0 + 64, nv-1)];
  const size_t asrc0 = (size_t)tok0 * DIM + ac*8;
  const size_t asrc1 = (size_t)tok1 * DIM + ac*8;
  const int dg = t >> 5;
  const int hq = t & 31;
  const float* w1p = w1 + (size_t)e * DIM * NH + (size_t)(h0 + hq*4);
  const float* w3p = w3 + (size_t)e * DIM * NH + (size_t)(h0 + hq*4);
  const int wid = t >> 6, l = t & 63;
  const int wr = wid >> 1, wc = wid & 1;
  const int lr = l & 15,  lk = l >> 4;
  f32x4 acc1[4][4], acc3[4][4];
  #pragma unroll
  for (int m=0;m<4;m++)
    #pragma unroll
    for (int n=0;n<4;n++){ acc1[m][n] = (f32x4)0.f; acc3[m][n] = (f32x4)0.f; }
  for (int kk=0; kk<DIM/32; ++kk){
    const int k0 = kk*32;
    __syncthreads();
    *(uint4*)&Al[ar0*32 + ac*8]      = *(const uint4*)(xbf + asrc0 + k0);
    *(uint4*)&Al[(ar0+64)*32 + ac*8] = *(const uint4*)(xbf + asrc1 + k0);
    {
      const float4 f0 = *(const float4*)(w1p + (size_t)(k0 + dg*4 + 0)*NH);
      const float4 f1 = *(const float4*)(w1p + (size_t)(k0 + dg*4 + 1)*NH);
      const float4 f2 = *(const float4*)(w1p + (size_t)(k0 + dg*4 + 2)*NH);
      const float4 f3 = *(const float4*)(w1p + (size_t)(k0 + dg*4 + 3)*NH);
      const float* p0=(const float*)&f0; const float* p1=(const float*)&f1;
      const float* p2=(const float*)&f2; const float* p3=(const float*)&f3;
      #pragma unroll
      for (int j=0;j<4;j++){
        ushort4 pk = make_ushort4(f2bf(p0[j]), f2bf(p1[j]), f2bf(p2[j]), f2bf(p3[j]));
        *(ushort4*)&B1l[(hq*4+j)*32 + dg*4] = pk;
      }
      const float4 g0 = *(const float4*)(w3p + (size_t)(k0 + dg*4 + 0)*NH);
      const float4 g1 = *(const float4*)(w3p + (size_t)(k0 + dg*4 + 1)*NH);
      const float4 g2 = *(const float4*)(w3p + (size_t)(k0 + dg*4 + 2)*NH);
      const float4 g3 = *(const float4*)(w3p + (size_t)(k0 + dg*4 + 3)*NH);
      const float* q0=(const float*)&g0; const float* q1=(const float*)&g1;
      const float* q2=(const float*)&g2; const float* q3=(const float*)&g3;
      #pragma unroll
      for (int j=0;j<4;j++){
        ushort4 pk = make_ushort4(f2bf(q0[j]), f2bf(q1[j]), f2bf(q2[j]), f2bf(q3[j]));
        *(ushort4*)&B3l[(hq*4+j)*32 + dg*4] = pk;
      }
    }
    __syncthreads();
    bf16x8 a[4], b1[4], b3[4];
    #pragma unroll
    for (int m=0;m<4;m++) a[m] = *(const bf16x8*)&Al[(wr*64 + m*16 + lr)*32 + lk*8];
    #pragma unroll
    for (int n=0;n<4;n++){
      b1[n] = *(const bf16x8*)&B1l[(wc*64 + n*16 + lr)*32 + lk*8];
      b3[n] = *(const bf16x8*)&B3l[(wc*64 + n*16 + lr)*32 + lk*8];
    }
    #pragma unroll
    for (int m=0;m<4;m++)
      #pragma unroll
      for (int n=0;n<4;n++){
        acc1[m][n] = MFMA16(a[m], b1[n], acc1[m][n]);
        acc3[m][n] = MFMA16(a[m], b3[n], acc3[m][n]);
      }
  }
  #pragma unroll
  for (int m=0;m<4;m++){
    #pragma unroll
    for (int i=0;i<4;i++){
      const int r = wr*64 + m*16 + lk*4 + i;
      if (r < nv){
        const size_t rowbase = (size_t)(base + r) * NH;
        #pragma unroll
        for (int n=0;n<4;n++){
          float z  = acc1[m][n][i];
          float p3 = acc3[m][n][i];
          float hv = (z / (1.f + __expf(-z))) * p3;
          hbuf[rowbase + h0 + wc*64 + n*16 + lr] = f2bf(hv);
        }
      }
    }
  }
}

__global__ __launch_bounds__(256) void gemm2_k(
    const unsigned short* __restrict__ hbuf,
    const float* __restrict__ w2,
    float* __restrict__ out,
    const int* __restrict__ row_tok, const float* __restrict__ row_w,
    const int* __restrict__ counts, const int* __restrict__ offs)
{
  __shared__ unsigned short Al[128*32];
  __shared__ unsigned short Bl[128*32];
  const int e   = blockIdx.y >> 6;
  const int rb  = blockIdx.y & 63;
  const int cnt = counts[e];
  const int row0 = rb * 128;
  if (row0 >= cnt) return;
  const int nv   = min(128, cnt - row0);
  const int base = offs[e] + row0;
  const int d0   = blockIdx.x * 128;
  const int t  = threadIdx.x;
  const int ar0 = t >> 2;
  const int ac  = t & 3;
  const size_t asrc0 = (size_t)(base + min(ar0,      nv-1)) * NH + ac*8;
  const size_t asrc1 = (size_t)(base + min(ar0 + 64, nv-1)) * NH + ac*8;
  const int dg = t >> 5;
  const int hq = t & 31;
  const float* w2p = w2 + (size_t)e * NH * DIM + (size_t)(d0 + hq*4);
  const int wid = t >> 6, l = t & 63;
  const int wr = wid >> 1, wc = wid & 1;
  const int lr = l & 15,  lk = l >> 4;
  f32x4 acc[4][4];
  #pragma unroll
  for (int m=0;m<4;m++)
    #pragma unroll
    for (int n=0;n<4;n++) acc[m][n] = (f32x4)0.f;
  for (int kk=0; kk<NH/32; ++kk){
    const int k0 = kk*32;
    __syncthreads();
    *(uint4*)&Al[ar0*32 + ac*8]      = *(const uint4*)(hbuf + asrc0 + k0);
    *(uint4*)&Al[(ar0+64)*32 + ac*8] = *(const uint4*)(hbuf + asrc1 + k0);
    {
      const float4 f0 = *(const float4*)(w2p + (size_t)(k0 + dg*4 + 0)*DIM);
      const float4 f1 = *(const float4*)(w2p + (size_t)(k0 + dg*4 + 1)*DIM);
      const float4 f2 = *(const float4*)(w2p + (size_t)(k0 + dg*4 + 2)*DIM);
      const float4 f3 = *(const float4*)(w2p + (size_t)(k0 + dg*4 + 3)*DIM);
      const float* p0=(const float*)&f0; const float* p1=(const float*)&f1;
      const float* p2=(const float*)&f2; const float* p3=(const float*)&f3;
      #pragma unroll
      for (int j=0;j<4;j++){
        ushort4 pk = make_ushort4(f2bf(p0[j]), f2bf(p1[j]), f2bf(p2[j]), f2bf(p3[j]));
        *(ushort4*)&Bl[(hq*4+j)*32 + dg*4] = pk;
      }
    }
    __syncthreads();
    bf16x8 a[4], b[4];
    #pragma unroll
    for (int m=0;m<4;m++) a[m] = *(const bf16x8*)&Al[(wr*64 + m*16 + lr)*32 + lk*8];
    #pragma unroll
    for (int n=0;n<4;n++)  b[n] = *(const bf16x8*)&Bl[(wc*64 + n*16 + lr)*32 + lk*8];
    #pragma unroll
    for (int m=0;m<4;m++)
      #pragma unroll
      for (int n=0;n<4;n++)
        acc[m][n] = MFMA16(a[m], b[n], acc[m][n]);
  }
  #pragma unroll
  for (int m=0;m<4;m++){
    #pragma unroll
    for (int i=0;i<4;i++){
      const int r = wr*64 + m*16 + lk*4 + i;
      if (r < nv){
        const int flat = base + r;
        const int tok  = row_tok[flat];
        const float wgt = row_w[flat];
        float* orow = out + (size_t)tok * DIM + d0 + wc*64;
        #pragma unroll
        for (int n=0;n<4;n++)
          atomicAdd(&orow[n*16 + lr], acc[m][n][i] * wgt);
      }
    }
  }
}

// ---------------- launch ----------------

extern "C" void kernel_launch(void* const* d_in, const int* in_sizes, int n_in,
                              void* d_out, int out_size, void* d_ws, size_t ws_size,
                              hipStream_t stream) {
  (void)in_sizes; (void)n_in; (void)out_size;
  const float* x   = (const float*)d_in[0];
  const float* rw  = (const float*)d_in[1];
  const float* w1  = (const float*)d_in[2];
  const float* w2  = (const float*)d_in[3];
  const float* w3  = (const float*)d_in[4];
  float* out = (float*)d_out;
  char* ws = (char*)d_ws;

  const size_t SZ_XBF  = (size_t)T_TOK*DIM*2;
  const size_t SZ_HBUF = (size_t)NROWS*NH*2;
  const size_t SZ_WT   = (size_t)NE*NH*DIM*2;
  const size_t SZ_SMALL = (size_t)NROWS*4*2 + (size_t)T_TOK*2*4*2 + 3*64*4 + 4096;
  const size_t NEED_FAST = SZ_XBF + SZ_HBUF + 2*SZ_WT + SZ_SMALL;
  const size_t NEED_FULL = SZ_XBF + SZ_HBUF + 3*SZ_WT + SZ_SMALL;

  if (ws_size >= NEED_FAST) {
    const bool full = (ws_size >= NEED_FULL);
    size_t off = 0;
    unsigned short* xbf  = (unsigned short*)(ws + off); off += SZ_XBF;
    unsigned short* hbuf = (unsigned short*)(ws + off); off += SZ_HBUF;
    unsigned short* w1t  = (unsigned short*)(ws + off); off += SZ_WT;
    unsigned short* w3t  = (unsigned short*)(ws + off); off += SZ_WT;
    unsigned short* w2t;
    if (full){ w2t = (unsigned short*)(ws + off); off += SZ_WT; }
    else      { w2t = w1t; }  // overlay (w1t dead after gemm1)
    int*   row_tok = (int*)  (ws + off); off += NROWS*4;
    float* row_w   = (float*)(ws + off); off += NROWS*4;
    int*   topk_e  = (int*)  (ws + off); off += T_TOK*2*4;
    float* topk_w  = (float*)(ws + off); off += T_TOK*2*4;
    int*   counts  = (int*)  (ws + off); off += 64;
    int*   offs    = (int*)  (ws + off); off += 64;
    int*   cursor  = (int*)  (ws + off); off += 64;

    zero_init_k<<<2048, 256, 0, stream>>>((float4*)out, counts, cursor);
    router_k   <<<T_TOK, 64, 0, stream>>>(x, rw, xbf, topk_e, topk_w, counts);
    prefix_k   <<<1, 64, 0, stream>>>(counts, offs);
    scatter_k  <<<(T_TOK+255)/256, 256, 0, stream>>>(topk_e, topk_w, offs, cursor, row_tok, row_w);
    if (full){
      transpA_k <<<dim3(704, 24), 256, 0, stream>>>(w1, w3, w2, w1t, w3t, w2t, 0);
      gemm1_p   <<<dim3(64, 176), 512, 0, stream>>>(xbf, w1t, w3t, hbuf, row_tok, counts, offs);
      gemm2_v   <<<dim3(64, NE*8), 512, 0, stream>>>(hbuf, w2t, out, row_tok, row_w, counts, offs);
    } else {
      transpA_k <<<dim3(704, 16), 256, 0, stream>>>(w1, w3, w2, w1t, w3t, w2t, 0);
      gemm1_p   <<<dim3(64, 176), 512, 0, stream>>>(xbf, w1t, w3t, hbuf, row_tok, counts, offs);
      transpA_k <<<dim3(704, 8), 256, 0, stream>>>(w1, w3, w2, w1t, w3t, w2t, 16);
      gemm2_v   <<<dim3(64, NE*8), 512, 0, stream>>>(hbuf, w2t, out, row_tok, row_w, counts, offs);
    }
  } else {
    size_t off = 0;
    unsigned short* xbf  = (unsigned short*)(ws + off); off += SZ_XBF;
    unsigned short* hbuf = (unsigned short*)(ws + off); off += SZ_HBUF;
    int*   row_tok = (int*)  (ws + off); off += NROWS*4;
    float* row_w   = (float*)(ws + off); off += NROWS*4;
    int*   topk_e  = (int*)  (ws + off); off += T_TOK*2*4;
    float* topk_w  = (float*)(ws + off); off += T_TOK*2*4;
    int*   counts  = (int*)  (ws + off); off += 64;
    int*   offs    = (int*)  (ws + off); off += 64;
    int*   cursor  = (int*)  (ws + off); off += 64;

    zero_init_k<<<2048, 256, 0, stream>>>((float4*)out, counts, cursor);
    router_k   <<<T_TOK, 64, 0, stream>>>(x, rw, xbf, topk_e, topk_w, counts);
    prefix_k   <<<1, 64, 0, stream>>>(counts, offs);
    scatter_k  <<<(T_TOK+255)/256, 256, 0, stream>>>(topk_e, topk_w, offs, cursor, row_tok, row_w);
    gemm1_k    <<<dim3(NH/128, NE*64), 256, 0, stream>>>(xbf, w1, w3, hbuf, row_tok, counts, offs);
    gemm2_k    <<<dim3(DIM/128, NE*64), 256, 0, stream>>>(hbuf, w2, out, row_tok, row_w, counts, offs);
  }
}

// Round 12
// 755.932 us; speedup vs baseline: 1.0139x; 1.0139x over previous
//
#include <hip/hip_runtime.h>
#include <stdint.h>

#define T_TOK 8192
#define DIM   1024
#define NE    8
#define NH    2816
#define NROWS (T_TOK*2)

typedef __attribute__((ext_vector_type(8))) __bf16 bf16x8;
typedef __attribute__((ext_vector_type(4))) float  f32x4;
typedef __attribute__((ext_vector_type(8))) unsigned short ushort8;

typedef __attribute__((address_space(1))) const unsigned int g_as1;
typedef __attribute__((address_space(3))) unsigned int l_as3;
#define GLL(g, l) __builtin_amdgcn_global_load_lds((g_as1*)(g), (l_as3*)(l), 16, 0, 0)
#define MFMA16(a,b,c) __builtin_amdgcn_mfma_f32_16x16x32_bf16(a,b,c,0,0,0)

__device__ __forceinline__ unsigned short f2bf(float f){
  union { float f; uint32_t u; } v; v.f = f;
  uint32_t r = (v.u + 0x7FFFu + ((v.u >> 16) & 1u)) >> 16;
  return (unsigned short)r;
}

// ---------------- zero+init (fused) ----------------

__global__ void zero_init_k(float4* __restrict__ out, int* counts, int* cursor){
  if (blockIdx.x == 0 && threadIdx.x < NE){ counts[threadIdx.x] = 0; cursor[threadIdx.x] = 0; }
  int i = blockIdx.x*blockDim.x + threadIdx.x;
  const int n4 = T_TOK*DIM/4;
  const float4 z = make_float4(0.f,0.f,0.f,0.f);
  for (; i < n4; i += gridDim.x*blockDim.x) out[i] = z;
}

__global__ void cvt_k(const float* __restrict__ x, unsigned short* __restrict__ xbf){
  int i = blockIdx.x*blockDim.x + threadIdx.x;
  const int total = T_TOK*DIM/8;
  for (; i < total; i += gridDim.x*blockDim.x){
    const float4 a = *(const float4*)(x + (size_t)i*8);
    const float4 b = *(const float4*)(x + (size_t)i*8 + 4);
    ushort4 lo = make_ushort4(f2bf(a.x), f2bf(a.y), f2bf(a.z), f2bf(a.w));
    ushort4 hi = make_ushort4(f2bf(b.x), f2bf(b.y), f2bf(b.z), f2bf(b.w));
    *(ushort4*)(xbf + (size_t)i*8)     = lo;
    *(ushort4*)(xbf + (size_t)i*8 + 4) = hi;
  }
}

// ---------------- fused transpose-convert: f32 [R][C] -> bf16 [C][R] ----------------

__global__ __launch_bounds__(256) void transpA_k(
    const float* __restrict__ w1, const float* __restrict__ w3,
    const float* __restrict__ w2,
    unsigned short* __restrict__ w1t, unsigned short* __restrict__ w3t,
    unsigned short* __restrict__ w2t, int zbase)
{
  __shared__ unsigned short Tl[64*72];
  const int z = zbase + blockIdx.y;
  const int f = blockIdx.x;
  const size_t DS = (size_t)DIM*NH;
  const float* src; unsigned short* dst; int R, C, rt, ct;
  if (z < 16){
    R = DIM; C = NH; rt = f/44; ct = f - rt*44;
    const int e = z & 7;
    src = (z < 8 ? w1 : w3) + (size_t)e*DS;
    dst = (z < 8 ? w1t : w3t) + (size_t)e*DS;
  } else {
    R = NH; C = DIM; rt = f/16; ct = f - rt*16;
    const int e = z - 16;
    src = w2 + (size_t)e*DS;
    dst = w2t + (size_t)e*DS;
  }
  const int r0 = rt*64, c0 = ct*64;
  const int t = threadIdx.x;
  #pragma unroll
  for (int i=0;i<4;i++){
    const int r  = (t>>4) + i*16;
    const int cq = t & 15;
    const float4 v = *(const float4*)(src + (size_t)(r0+r)*C + c0 + cq*4);
    Tl[(cq*4+0)*72 + r] = f2bf(v.x);
    Tl[(cq*4+1)*72 + r] = f2bf(v.y);
    Tl[(cq*4+2)*72 + r] = f2bf(v.z);
    Tl[(cq*4+3)*72 + r] = f2bf(v.w);
  }
  __syncthreads();
  #pragma unroll
  for (int i=0;i<2;i++){
    const int c  = i*32 + (t>>3);
    const int r8 = (t&7)*8;
    const ushort8 v = *(const ushort8*)&Tl[c*72 + r8];
    *(ushort8*)(dst + (size_t)(c0+c)*R + r0 + r8) = v;
  }
}

// ---------------- router (fused with x->bf16 convert) ----------------

__global__ void router_k(const float* __restrict__ x, const float* __restrict__ rw,
                         unsigned short* __restrict__ xbf,
                         int* __restrict__ topk_e, float* __restrict__ topk_w,
                         int* __restrict__ counts){
  const int t = blockIdx.x;
  const int l = threadIdx.x;
  const float* xr = x + (size_t)t * DIM;
  unsigned short* xo = xbf + (size_t)t * DIM;
  float acc[NE];
  #pragma unroll
  for (int e=0;e<NE;e++) acc[e] = 0.f;
  #pragma unroll
  for (int i=0;i<4;i++){
    const int idx = l*4 + i*256;
    const float4 xv = *(const float4*)(xr + idx);
    ushort4 pk = make_ushort4(f2bf(xv.x), f2bf(xv.y), f2bf(xv.z), f2bf(xv.w));
    *(ushort4*)(xo + idx) = pk;
    #pragma unroll
    for (int e=0;e<NE;e++){
      const float4 wv = *(const float4*)(rw + e*DIM + idx);
      acc[e] += xv.x*wv.x + xv.y*wv.y + xv.z*wv.z + xv.w*wv.w;
    }
  }
  #pragma unroll
  for (int e=0;e<NE;e++){
    float v = acc[e];
    #pragma unroll
    for (int off=32; off; off>>=1) v += __shfl_xor(v, off);
    acc[e] = v;
  }
  if (l == 0){
    int e0 = 0; float v0 = acc[0];
    #pragma unroll
    for (int e=1;e<NE;e++) if (acc[e] > v0){ v0 = acc[e]; e0 = e; }
    int e1 = -1; float v1 = -1e30f;
    #pragma unroll
    for (int e=0;e<NE;e++) if (e != e0 && acc[e] > v1){ v1 = acc[e]; e1 = e; }
    float ex = __expf(v1 - v0);
    float s  = 1.f + ex;
    topk_e[t*2]   = e0;  topk_e[t*2+1] = e1;
    topk_w[t*2]   = 1.f/s; topk_w[t*2+1] = ex/s;
    atomicAdd(&counts[e0], 1);
    atomicAdd(&counts[e1], 1);
  }
}

__global__ void prefix_k(const int* __restrict__ counts, int* __restrict__ offs){
  if (threadIdx.x == 0 && blockIdx.x == 0){
    int s = 0;
    for (int e=0;e<NE;e++){ offs[e] = s; s += counts[e]; }
  }
}

__global__ void scatter_k(const int* __restrict__ topk_e, const float* __restrict__ topk_w,
                          const int* __restrict__ offs, int* __restrict__ cursor,
                          int* __restrict__ row_tok, float* __restrict__ row_w){
  int t = blockIdx.x*blockDim.x + threadIdx.x;
  if (t >= T_TOK) return;
  #pragma unroll
  for (int k=0;k<2;k++){
    int e = topk_e[t*2+k];
    int p = atomicAdd(&cursor[e], 1);
    int flat = offs[e] + p;
    row_tok[flat] = t;
    row_w[flat]   = topk_w[t*2+k];
  }
}

// ============ FAST GEMMs ============
// LDS-port model (r11): util ~ (M_mfma*5/4)/(R_reads*12) per step; need M/R >= 2
// with <=64 AGPR acc and >=1024 active blocks. gemm1_p: M/R=16/8=2.0 (33% meas).

// GEMM1 (round-6 proven): 128x128x2 tile, 8 waves (2x4), BK=32, ring-3, vmcnt(3)
__global__ __launch_bounds__(512,2) void gemm1_p(
    const unsigned short* __restrict__ xbf,
    const unsigned short* __restrict__ w1t, const unsigned short* __restrict__ w3t,
    unsigned short* __restrict__ hbuf,
    const int* __restrict__ row_tok,
    const int* __restrict__ counts, const int* __restrict__ offs)
{
  __shared__ unsigned short As [3][128*32];
  __shared__ unsigned short B1s[3][128*32];
  __shared__ unsigned short B3s[3][128*32];   // 72 KB total

  const int i   = blockIdx.y*64 + blockIdx.x;
  const int lid = (i & 7)*1408 + (i >> 3);
  const int e   = lid / 1408;
  const int rem = lid - e*1408;
  const int h0  = (rem >> 6) * 128;
  const int rb  = rem & 63;

  const int cnt = counts[e];
  const int row0 = rb * 128;
  if (row0 >= cnt) return;
  const int nv   = min(128, cnt - row0);
  const int base = offs[e] + row0;
  const int NK   = DIM/32;

  const int t = threadIdx.x;
  const int r_loc = t >> 2, sct = t & 3;
  const int csw = (sct ^ ((r_loc >> 1) & 3)) * 8;
  const int tok = row_tok[base + min(r_loc, nv-1)];
  const unsigned short* aS  = xbf + (size_t)tok*DIM + csw;
  const unsigned short* b1S = w1t + ((size_t)(e*NH + h0) + r_loc)*DIM + csw;
  const unsigned short* b3S = w3t + ((size_t)(e*NH + h0) + r_loc)*DIM + csw;
  const int lo = t*16;

  const int wid = t >> 6, l = t & 63;
  const int wr = wid >> 2, wc = wid & 3;
  const int lr = l & 15,  lk = l >> 4;
  const int rc = (lk ^ ((lr >> 1) & 3)) * 8;

  f32x4 acc1[4][2], acc3[4][2];
  #pragma unroll
  for (int m=0;m<4;m++)
    #pragma unroll
    for (int n=0;n<2;n++){ acc1[m][n] = (f32x4)0.f; acc3[m][n] = (f32x4)0.f; }

  GLL(aS,    (char*)As[0]+lo); GLL(b1S,    (char*)B1s[0]+lo); GLL(b3S,    (char*)B3s[0]+lo);
  GLL(aS+32, (char*)As[1]+lo); GLL(b1S+32, (char*)B1s[1]+lo); GLL(b3S+32, (char*)B3s[1]+lo);

  for (int kt=0; kt<NK; ++kt){
    if (kt < NK-1) asm volatile("s_waitcnt vmcnt(3)" ::: "memory");
    else           asm volatile("s_waitcnt vmcnt(0)" ::: "memory");
    __builtin_amdgcn_s_barrier();

    if (kt+2 < NK){
      const int kA = (kt+2)*32;
      char* ad  = (char*)As [(kt+2)%3];
      char* b1d = (char*)B1s[(kt+2)%3];
      char* b3d = (char*)B3s[(kt+2)%3];
      GLL(aS+kA, ad+lo); GLL(b1S+kA, b1d+lo); GLL(b3S+kA, b3d+lo);
    }

    const unsigned short* Ab  = As [kt%3];
    const unsigned short* B1b = B1s[kt%3];
    const unsigned short* B3b = B3s[kt%3];

    bf16x8 a[4], b1[2], b3[2];
    #pragma unroll
    for (int m=0;m<4;m++) a[m] = *(const bf16x8*)&Ab[(wr*64 + m*16 + lr)*32 + rc];
    #pragma unroll
    for (int n=0;n<2;n++){
      b1[n] = *(const bf16x8*)&B1b[(wc*32 + n*16 + lr)*32 + rc];
      b3[n] = *(const bf16x8*)&B3b[(wc*32 + n*16 + lr)*32 + rc];
    }
    __builtin_amdgcn_s_setprio(1);
    #pragma unroll
    for (int m=0;m<4;m++)
      #pragma unroll
      for (int n=0;n<2;n++){
        acc1[m][n] = MFMA16(a[m], b1[n], acc1[m][n]);
        acc3[m][n] = MFMA16(a[m], b3[n], acc3[m][n]);
      }
    __builtin_amdgcn_s_setprio(0);
  }

  #pragma unroll
  for (int m=0;m<4;m++){
    #pragma unroll
    for (int i2=0;i2<4;i2++){
      const int r = wr*64 + m*16 + lk*4 + i2;
      if (r < nv){
        const size_t rowbase = (size_t)(base + r) * NH;
        #pragma unroll
        for (int n=0;n<2;n++){
          float z  = acc1[m][n][i2];
          float p3 = acc3[m][n][i2];
          float hv = (z / (1.f + __expf(-z))) * p3;
          hbuf[rowbase + h0 + wc*32 + n*16 + lr] = f2bf(hv);
        }
      }
    }
  }
}

// GEMM2 v3: 128x128 tile, 4 waves (2x2), per-wave 64x64 out, acc[4][4]=64 AGPR,
// M/R = 16/8 = 2.0. BK=32 ring-3 (48 KB -> 3 blocks/CU), 4 GLL/step, vmcnt(4).
__global__ __launch_bounds__(256,3) void gemm2_s(
    const unsigned short* __restrict__ hbuf,
    const unsigned short* __restrict__ w2t,
    float* __restrict__ out,
    const int* __restrict__ row_tok, const float* __restrict__ row_w,
    const int* __restrict__ counts, const int* __restrict__ offs)
{
  __shared__ unsigned short As[3][128*32];   // 24 KB
  __shared__ unsigned short Bs[3][128*32];   // 24 KB -> 48 KB

  const int i   = blockIdx.y*64 + blockIdx.x;     // grid (64, NE*8)
  const int lid = (i & 7)*512 + (i >> 3);
  const int e   = lid >> 9;
  const int rem = lid & 511;
  const int d0  = (rem >> 6) * 128;
  const int rb  = rem & 63;

  const int cnt = counts[e];
  const int row0 = rb * 128;
  if (row0 >= cnt) return;
  const int nv   = min(128, cnt - row0);
  const int base = offs[e] + row0;
  const int NK   = NH/32;                         // 88

  const int t = threadIdx.x;                      // 256 threads
  const int r_loc = t >> 2, sct = t & 3;          // rows 0..63, 4 chunks
  const int csw = (sct ^ ((r_loc >> 1) & 3)) * 8; // row+64 preserves XOR (64%8==0)
  const unsigned short* aS0 = hbuf + (size_t)(base + min(r_loc,      nv-1))*NH + csw;
  const unsigned short* aS1 = hbuf + (size_t)(base + min(r_loc + 64, nv-1))*NH + csw;
  const unsigned short* bS0 = w2t + ((size_t)(e*DIM + d0) + r_loc)*NH + csw;
  const unsigned short* bS1 = bS0 + (size_t)64*NH;
  const int lo0 = t*16, lo1 = 4096 + t*16;

  const int wid = t >> 6, l = t & 63;
  const int wr = wid >> 1, wc = wid & 1;          // 2x2 waves, 64x64 out each
  const int lr = l & 15,  lk = l >> 4;
  const int rc = (lk ^ ((lr >> 1) & 3)) * 8;

  f32x4 acc[4][4];                                // 64 AGPR
  #pragma unroll
  for (int m=0;m<4;m++)
    #pragma unroll
    for (int n=0;n<4;n++) acc[m][n] = (f32x4)0.f;

  // prologue: tiles 0 and 1 (4 GLL each)
  GLL(aS0,    (char*)As[0]+lo0); GLL(aS1,    (char*)As[0]+lo1);
  GLL(bS0,    (char*)Bs[0]+lo0); GLL(bS1,    (char*)Bs[0]+lo1);
  GLL(aS0+32, (char*)As[1]+lo0); GLL(aS1+32, (char*)As[1]+lo1);
  GLL(bS0+32, (char*)Bs[1]+lo0); GLL(bS1+32, (char*)Bs[1]+lo1);

  for (int kt=0; kt<NK; ++kt){
    if (kt < NK-1) asm volatile("s_waitcnt vmcnt(4)" ::: "memory");
    else           asm volatile("s_waitcnt vmcnt(0)" ::: "memory");
    __builtin_amdgcn_s_barrier();

    if (kt+2 < NK){
      const int kA = (kt+2)*32;
      char* ad = (char*)As[(kt+2)%3];
      char* bd = (char*)Bs[(kt+2)%3];
      GLL(aS0+kA, ad+lo0); GLL(aS1+kA, ad+lo1);
      GLL(bS0+kA, bd+lo0); GLL(bS1+kA, bd+lo1);
    }

    const unsigned short* Ab = As[kt%3];
    const unsigned short* Bb = Bs[kt%3];

    bf16x8 a[4], b[4];
    #pragma unroll
    for (int m=0;m<4;m++) a[m] = *(const bf16x8*)&Ab[(wr*64 + m*16 + lr)*32 + rc];
    #pragma unroll
    for (int n=0;n<4;n++)  b[n] = *(const bf16x8*)&Bb[(wc*64 + n*16 + lr)*32 + rc];
    __builtin_amdgcn_s_setprio(1);
    #pragma unroll
    for (int m=0;m<4;m++)
      #pragma unroll
      for (int n=0;n<4;n++)
        acc[m][n] = MFMA16(a[m], b[n], acc[m][n]);
    __builtin_amdgcn_s_setprio(0);
  }

  #pragma unroll
  for (int m=0;m<4;m++){
    #pragma unroll
    for (int i2=0;i2<4;i2++){
      const int r = wr*64 + m*16 + lk*4 + i2;
      if (r < nv){
        const int flat = base + r;
        const int tok  = row_tok[flat];
        const float wgt = row_w[flat];
        float* orow = out + (size_t)tok * DIM + d0 + wc*64;
        #pragma unroll
        for (int n=0;n<4;n++)
          atomicAdd(&orow[n*16 + lr], acc[m][n][i2] * wgt);
      }
    }
  }
}

// ============ SLOW FALLBACK (f32 weights, small ws) ============

__global__ __launch_bounds__(256) void gemm1_k(
    const unsigned short* __restrict__ xbf,
    const float* __restrict__ w1, const float* __restrict__ w3,
    unsigned short* __restrict__ hbuf,
    const int* __restrict__ row_tok,
    const int* __restrict__ counts, const int* __restrict__ offs)
{
  __shared__ unsigned short Al [128*32];
  __shared__ unsigned short B1l[128*32];
  __shared__ unsigned short B3l[128*32];
  const int e   = blockIdx.y >> 6;
  const int rb  = blockIdx.y & 63;
  const int cnt = counts[e];
  const int row0 = rb * 128;
  if (row0 >= cnt) return;
  const int nv   = min(128, cnt - row0);
  const int base = offs[e] + row0;
  const int h0   = blockIdx.x * 128;
  const int t  = threadIdx.x;
  const int ar0 = t >> 2;
  const int ac  = t & 3;
  const int tok0 = row_tok[base + min(ar0,      nv-1)];
  const int tok1 = row_tok[base + min(ar0 + 64, nv-1)];
  const size_t asrc0 = (size_t)tok0 * DIM + ac*8;
  const size_t asrc1 = (size_t)tok1 * DIM + ac*8;
  const int dg = t >> 5;
  const int hq = t & 31;
  const float* w1p = w1 + (size_t)e * DIM * NH + (size_t)(h0 + hq*4);
  const float* w3p = w3 + (size_t)e * DIM * NH + (size_t)(h0 + hq*4);
  const int wid = t >> 6, l = t & 63;
  const int wr = wid >> 1, wc = wid & 1;
  const int lr = l & 15,  lk = l >> 4;
  f32x4 acc1[4][4], acc3[4][4];
  #pragma unroll
  for (int m=0;m<4;m++)
    #pragma unroll
    for (int n=0;n<4;n++){ acc1[m][n] = (f32x4)0.f; acc3[m][n] = (f32x4)0.f; }
  for (int kk=0; kk<DIM/32; ++kk){
    const int k0 = kk*32;
    __syncthreads();
    *(uint4*)&Al[ar0*32 + ac*8]      = *(const uint4*)(xbf + asrc0 + k0);
    *(uint4*)&Al[(ar0+64)*32 + ac*8] = *(const uint4*)(xbf + asrc1 + k0);
    {
      const float4 f0 = *(const float4*)(w1p + (size_t)(k0 + dg*4 + 0)*NH);
      const float4 f1 = *(const float4*)(w1p + (size_t)(k0 + dg*4 + 1)*NH);
      const float4 f2 = *(const float4*)(w1p + (size_t)(k0 + dg*4 + 2)*NH);
      const float4 f3 = *(const float4*)(w1p + (size_t)(k0 + dg*4 + 3)*NH);
      const float* p0=(const float*)&f0; const float* p1=(const float*)&f1;
      const float* p2=(const float*)&f2; const float* p3=(const float*)&f3;
      #pragma unroll
      for (int j=0;j<4;j++){
        ushort4 pk = make_ushort4(f2bf(p0[j]), f2bf(p1[j]), f2bf(p2[j]), f2bf(p3[j]));
        *(ushort4*)&B1l[(hq*4+j)*32 + dg*4] = pk;
      }
      const float4 g0 = *(const float4*)(w3p + (size_t)(k0 + dg*4 + 0)*NH);
      const float4 g1 = *(const float4*)(w3p + (size_t)(k0 + dg*4 + 1)*NH);
      const float4 g2 = *(const float4*)(w3p + (size_t)(k0 + dg*4 + 2)*NH);
      const float4 g3 = *(const float4*)(w3p + (size_t)(k0 + dg*4 + 3)*NH);
      const float* q0=(const float*)&g0; const float* q1=(const float*)&g1;
      const float* q2=(const float*)&g2; const float* q3=(const float*)&g3;
      #pragma unroll
      for (int j=0;j<4;j++){
        ushort4 pk = make_ushort4(f2bf(q0[j]), f2bf(q1[j]), f2bf(q2[j]), f2bf(q3[j]));
        *(ushort4*)&B3l[(hq*4+j)*32 + dg*4] = pk;
      }
    }
    __syncthreads();
    bf16x8 a[4], b1[4], b3[4];
    #pragma unroll
    for (int m=0;m<4;m++) a[m] = *(const bf16x8*)&Al[(wr*64 + m*16 + lr)*32 + lk*8];
    #pragma unroll
    for (int n=0;n<4;n++){
      b1[n] = *(const bf16x8*)&B1l[(wc*64 + n*16 + lr)*32 + lk*8];
      b3[n] = *(const bf16x8*)&B3l[(wc*64 + n*16 + lr)*32 + lk*8];
    }
    #pragma unroll
    for (int m=0;m<4;m++)
      #pragma unroll
      for (int n=0;n<4;n++){
        acc1[m][n] = MFMA16(a[m], b1[n], acc1[m][n]);
        acc3[m][n] = MFMA16(a[m], b3[n], acc3[m][n]);
      }
  }
  #pragma unroll
  for (int m=0;m<4;m++){
    #pragma unroll
    for (int i=0;i<4;i++){
      const int r = wr*64 + m*16 + lk*4 + i;
      if (r < nv){
        const size_t rowbase = (size_t)(base + r) * NH;
        #pragma unroll
        for (int n=0;n<4;n++){
          float z  = acc1[m][n][i];
          float p3 = acc3[m][n][i];
          float hv = (z / (1.f + __expf(-z))) * p3;
          hbuf[rowbase + h0 + wc*64 + n*16 + lr] = f2bf(hv);
        }
      }
    }
  }
}

__global__ __launch_bounds__(256) void gemm2_k(
    const unsigned short* __restrict__ hbuf,
    const float* __restrict__ w2,
    float* __restrict__ out,
    const int* __restrict__ row_tok, const float* __restrict__ row_w,
    const int* __restrict__ counts, const int* __restrict__ offs)
{
  __shared__ unsigned short Al[128*32];
  __shared__ unsigned short Bl[128*32];
  const int e   = blockIdx.y >> 6;
  const int rb  = blockIdx.y & 63;
  const int cnt = counts[e];
  const int row0 = rb * 128;
  if (row0 >= cnt) return;
  const int nv   = min(128, cnt - row0);
  const int base = offs[e] + row0;
  const int d0   = blockIdx.x * 128;
  const int t  = threadIdx.x;
  const int ar0 = t >> 2;
  const int ac  = t & 3;
  const size_t asrc0 = (size_t)(base + min(ar0,      nv-1)) * NH + ac*8;
  const size_t asrc1 = (size_t)(base + min(ar0 + 64, nv-1)) * NH + ac*8;
  const int dg = t >> 5;
  const int hq = t & 31;
  const float* w2p = w2 + (size_t)e * NH * DIM + (size_t)(d0 + hq*4);
  const int wid = t >> 6, l = t & 63;
  const int wr = wid >> 1, wc = wid & 1;
  const int lr = l & 15,  lk = l >> 4;
  f32x4 acc[4][4];
  #pragma unroll
  for (int m=0;m<4;m++)
    #pragma unroll
    for (int n=0;n<4;n++) acc[m][n] = (f32x4)0.f;
  for (int kk=0; kk<NH/32; ++kk){
    const int k0 = kk*32;
    __syncthreads();
    *(uint4*)&Al[ar0*32 + ac*8]      = *(const uint4*)(hbuf + asrc0 + k0);
    *(uint4*)&Al[(ar0+64)*32 + ac*8] = *(const uint4*)(hbuf + asrc1 + k0);
    {
      const float4 f0 = *(const float4*)(w2p + (size_t)(k0 + dg*4 + 0)*DIM);
      const float4 f1 = *(const float4*)(w2p + (size_t)(k0 + dg*4 + 1)*DIM);
      const float4 f2 = *(const float4*)(w2p + (size_t)(k0 + dg*4 + 2)*DIM);
      const float4 f3 = *(const float4*)(w2p + (size_t)(k0 + dg*4 + 3)*DIM);
      const float* p0=(const float*)&f0; const float* p1=(const float*)&f1;
      const float* p2=(const float*)&f2; const float* p3=(const float*)&f3;
      #pragma unroll
      for (int j=0;j<4;j++){
        ushort4 pk = make_ushort4(f2bf(p0[j]), f2bf(p1[j]), f2bf(p2[j]), f2bf(p3[j]));
        *(ushort4*)&Bl[(hq*4+j)*32 + dg*4] = pk;
      }
    }
    __syncthreads();
    bf16x8 a[4], b[4];
    #pragma unroll
    for (int m=0;m<4;m++) a[m] = *(const bf16x8*)&Al[(wr*64 + m*16 + lr)*32 + lk*8];
    #pragma unroll
    for (int n=0;n<4;n++)  b[n] = *(const bf16x8*)&Bl[(wc*64 + n*16 + lr)*32 + lk*8];
    #pragma unroll
    for (int m=0;m<4;m++)
      #pragma unroll
      for (int n=0;n<4;n++)
        acc[m][n] = MFMA16(a[m], b[n], acc[m][n]);
  }
  #pragma unroll
  for (int m=0;m<4;m++){
    #pragma unroll
    for (int i=0;i<4;i++){
      const int r = wr*64 + m*16 + lk*4 + i;
      if (r < nv){
        const int flat = base + r;
        const int tok  = row_tok[flat];
        const float wgt = row_w[flat];
        float* orow = out + (size_t)tok * DIM + d0 + wc*64;
        #pragma unroll
        for (int n=0;n<4;n++)
          atomicAdd(&orow[n*16 + lr], acc[m][n][i] * wgt);
      }
    }
  }
}

// ---------------- launch ----------------

extern "C" void kernel_launch(void* const* d_in, const int* in_sizes, int n_in,
                              void* d_out, int out_size, void* d_ws, size_t ws_size,
                              hipStream_t stream) {
  (void)in_sizes; (void)n_in; (void)out_size;
  const float* x   = (const float*)d_in[0];
  const float* rw  = (const float*)d_in[1];
  const float* w1  = (const float*)d_in[2];
  const float* w2  = (const float*)d_in[3];
  const float* w3  = (const float*)d_in[4];
  float* out = (float*)d_out;
  char* ws = (char*)d_ws;

  const size_t SZ_XBF  = (size_t)T_TOK*DIM*2;
  const size_t SZ_HBUF = (size_t)NROWS*NH*2;
  const size_t SZ_WT   = (size_t)NE*NH*DIM*2;
  const size_t SZ_SMALL = (size_t)NROWS*4*2 + (size_t)T_TOK*2*4*2 + 3*64*4 + 4096;
  const size_t NEED_FAST = SZ_XBF + SZ_HBUF + 2*SZ_WT + SZ_SMALL;
  const size_t NEED_FULL = SZ_XBF + SZ_HBUF + 3*SZ_WT + SZ_SMALL;

  if (ws_size >= NEED_FAST) {
    const bool full = (ws_size >= NEED_FULL);
    size_t off = 0;
    unsigned short* xbf  = (unsigned short*)(ws + off); off += SZ_XBF;
    unsigned short* hbuf = (unsigned short*)(ws + off); off += SZ_HBUF;
    unsigned short* w1t  = (unsigned short*)(ws + off); off += SZ_WT;
    unsigned short* w3t  = (unsigned short*)(ws + off); off += SZ_WT;
    unsigned short* w2t;
    if (full){ w2t = (unsigned short*)(ws + off); off += SZ_WT; }
    else      { w2t = w1t; }  // overlay (w1t dead after gemm1)
    int*   row_tok = (int*)  (ws + off); off += NROWS*4;
    float* row_w   = (float*)(ws + off); off += NROWS*4;
    int*   topk_e  = (int*)  (ws + off); off += T_TOK*2*4;
    float* topk_w  = (float*)(ws + off); off += T_TOK*2*4;
    int*   counts  = (int*)  (ws + off); off += 64;
    int*   offs    = (int*)  (ws + off); off += 64;
    int*   cursor  = (int*)  (ws + off); off += 64;

    zero_init_k<<<2048, 256, 0, stream>>>((float4*)out, counts, cursor);
    router_k   <<<T_TOK, 64, 0, stream>>>(x, rw, xbf, topk_e, topk_w, counts);
    prefix_k   <<<1, 64, 0, stream>>>(counts, offs);
    scatter_k  <<<(T_TOK+255)/256, 256, 0, stream>>>(topk_e, topk_w, offs, cursor, row_tok, row_w);
    if (full){
      transpA_k <<<dim3(704, 24), 256, 0, stream>>>(w1, w3, w2, w1t, w3t, w2t, 0);
      gemm1_p   <<<dim3(64, 176), 512, 0, stream>>>(xbf, w1t, w3t, hbuf, row_tok, counts, offs);
      gemm2_s   <<<dim3(64, NE*8), 256, 0, stream>>>(hbuf, w2t, out, row_tok, row_w, counts, offs);
    } else {
      transpA_k <<<dim3(704, 16), 256, 0, stream>>>(w1, w3, w2, w1t, w3t, w2t, 0);
      gemm1_p   <<<dim3(64, 176), 512, 0, stream>>>(xbf, w1t, w3t, hbuf, row_tok, counts, offs);
      transpA_k <<<dim3(704, 8), 256, 0, stream>>>(w1, w3, w2, w1t, w3t, w2t, 16);
      gemm2_s   <<<dim3(64, NE*8), 256, 0, stream>>>(hbuf, w2t, out, row_tok, row_w, counts, offs);
    }
  } else {
    size_t off = 0;
    unsigned short* xbf  = (unsigned short*)(ws + off); off += SZ_XBF;
    unsigned short* hbuf = (unsigned short*)(ws + off); off += SZ_HBUF;
    int*   row_tok = (int*)  (ws + off); off += NROWS*4;
    float* row_w   = (float*)(ws + off); off += NROWS*4;
    int*   topk_e  = (int*)  (ws + off); off += T_TOK*2*4;
    float* topk_w  = (float*)(ws + off); off += T_TOK*2*4;
    int*   counts  = (int*)  (ws + off); off += 64;
    int*   offs    = (int*)  (ws + off); off += 64;
    int*   cursor  = (int*)  (ws + off); off += 64;

    zero_init_k<<<2048, 256, 0, stream>>>((float4*)out, counts, cursor);
    router_k   <<<T_TOK, 64, 0, stream>>>(x, rw, xbf, topk_e, topk_w, counts);
    prefix_k   <<<1, 64, 0, stream>>>(counts, offs);
    scatter_k  <<<(T_TOK+255)/256, 256, 0, stream>>>(topk_e, topk_w, offs, cursor, row_tok, row_w);
    gemm1_k    <<<dim3(NH/128, NE*64), 256, 0, stream>>>(xbf, w1, w3, hbuf, row_tok, counts, offs);
    gemm2_k    <<<dim3(DIM/128, NE*64), 256, 0, stream>>>(hbuf, w2, out, row_tok, row_w, counts, offs);
  }
}

// Round 13
// 704.845 us; speedup vs baseline: 1.0873x; 1.0725x over previous
//
#include <hip/hip_runtime.h>
#include <stdint.h>

#define T_TOK 8192
#define DIM   1024
#define NE    8
#define NH    2816
#define NROWS (T_TOK*2)

typedef __attribute__((ext_vector_type(8))) __bf16 bf16x8;
typedef __attribute__((ext_vector_type(4))) float  f32x4;
typedef __attribute__((ext_vector_type(8))) unsigned short ushort8;

typedef __attribute__((address_space(1))) const unsigned int g_as1;
typedef __attribute__((address_space(3))) unsigned int l_as3;
#define GLL(g, l) __builtin_amdgcn_global_load_lds((g_as1*)(g), (l_as3*)(l), 16, 0, 0)
#define MFMA16(a,b,c) __builtin_amdgcn_mfma_f32_16x16x32_bf16(a,b,c,0,0,0)

__device__ __forceinline__ unsigned short f2bf(float f){
  union { float f; uint32_t u; } v; v.f = f;
  uint32_t r = (v.u + 0x7FFFu + ((v.u >> 16) & 1u)) >> 16;
  return (unsigned short)r;
}
__device__ __forceinline__ float bf2f(unsigned short u){
  union { uint32_t u; float f; } v; v.u = ((uint32_t)u) << 16;
  return v.f;
}

// ---------------- init (fast path: counts/cursor only) ----------------

__global__ void init2_k(int* counts, int* cursor){
  int i = threadIdx.x;
  if (i < NE){ counts[i] = 0; cursor[i] = 0; }
}

// fallback path: zero out + init
__global__ void zero_init_k(float4* __restrict__ out, int* counts, int* cursor){
  if (blockIdx.x == 0 && threadIdx.x < NE){ counts[threadIdx.x] = 0; cursor[threadIdx.x] = 0; }
  int i = blockIdx.x*blockDim.x + threadIdx.x;
  const int n4 = T_TOK*DIM/4;
  const float4 z = make_float4(0.f,0.f,0.f,0.f);
  for (; i < n4; i += gridDim.x*blockDim.x) out[i] = z;
}

// ---------------- fused transpose-convert: f32 [R][C] -> bf16 [C][R] ----------------

__global__ __launch_bounds__(256) void transpA_k(
    const float* __restrict__ w1, const float* __restrict__ w3,
    const float* __restrict__ w2,
    unsigned short* __restrict__ w1t, unsigned short* __restrict__ w3t,
    unsigned short* __restrict__ w2t, int zbase)
{
  __shared__ unsigned short Tl[64*72];
  const int z = zbase + blockIdx.y;
  const int f = blockIdx.x;
  const size_t DS = (size_t)DIM*NH;
  const float* src; unsigned short* dst; int R, C, rt, ct;
  if (z < 16){
    R = DIM; C = NH; rt = f/44; ct = f - rt*44;
    const int e = z & 7;
    src = (z < 8 ? w1 : w3) + (size_t)e*DS;
    dst = (z < 8 ? w1t : w3t) + (size_t)e*DS;
  } else {
    R = NH; C = DIM; rt = f/16; ct = f - rt*16;
    const int e = z - 16;
    src = w2 + (size_t)e*DS;
    dst = w2t + (size_t)e*DS;
  }
  const int r0 = rt*64, c0 = ct*64;
  const int t = threadIdx.x;
  #pragma unroll
  for (int i=0;i<4;i++){
    const int r  = (t>>4) + i*16;
    const int cq = t & 15;
    const float4 v = *(const float4*)(src + (size_t)(r0+r)*C + c0 + cq*4);
    Tl[(cq*4+0)*72 + r] = f2bf(v.x);
    Tl[(cq*4+1)*72 + r] = f2bf(v.y);
    Tl[(cq*4+2)*72 + r] = f2bf(v.z);
    Tl[(cq*4+3)*72 + r] = f2bf(v.w);
  }
  __syncthreads();
  #pragma unroll
  for (int i=0;i<2;i++){
    const int c  = i*32 + (t>>3);
    const int r8 = (t&7)*8;
    const ushort8 v = *(const ushort8*)&Tl[c*72 + r8];
    *(ushort8*)(dst + (size_t)(c0+c)*R + r0 + r8) = v;
  }
}

// ---------------- router (fused with x->bf16 convert) ----------------

__global__ void router_k(const float* __restrict__ x, const float* __restrict__ rw,
                         unsigned short* __restrict__ xbf,
                         int* __restrict__ topk_e, float* __restrict__ topk_w,
                         int* __restrict__ counts){
  const int t = blockIdx.x;
  const int l = threadIdx.x;
  const float* xr = x + (size_t)t * DIM;
  unsigned short* xo = xbf + (size_t)t * DIM;
  float acc[NE];
  #pragma unroll
  for (int e=0;e<NE;e++) acc[e] = 0.f;
  #pragma unroll
  for (int i=0;i<4;i++){
    const int idx = l*4 + i*256;
    const float4 xv = *(const float4*)(xr + idx);
    ushort4 pk = make_ushort4(f2bf(xv.x), f2bf(xv.y), f2bf(xv.z), f2bf(xv.w));
    *(ushort4*)(xo + idx) = pk;
    #pragma unroll
    for (int e=0;e<NE;e++){
      const float4 wv = *(const float4*)(rw + e*DIM + idx);
      acc[e] += xv.x*wv.x + xv.y*wv.y + xv.z*wv.z + xv.w*wv.w;
    }
  }
  #pragma unroll
  for (int e=0;e<NE;e++){
    float v = acc[e];
    #pragma unroll
    for (int off=32; off; off>>=1) v += __shfl_xor(v, off);
    acc[e] = v;
  }
  if (l == 0){
    int e0 = 0; float v0 = acc[0];
    #pragma unroll
    for (int e=1;e<NE;e++) if (acc[e] > v0){ v0 = acc[e]; e0 = e; }
    int e1 = -1; float v1 = -1e30f;
    #pragma unroll
    for (int e=0;e<NE;e++) if (e != e0 && acc[e] > v1){ v1 = acc[e]; e1 = e; }
    float ex = __expf(v1 - v0);
    float s  = 1.f + ex;
    topk_e[t*2]   = e0;  topk_e[t*2+1] = e1;
    topk_w[t*2]   = 1.f/s; topk_w[t*2+1] = ex/s;
    atomicAdd(&counts[e0], 1);
    atomicAdd(&counts[e1], 1);
  }
}

__global__ void prefix_k(const int* __restrict__ counts, int* __restrict__ offs){
  if (threadIdx.x == 0 && blockIdx.x == 0){
    int s = 0;
    for (int e=0;e<NE;e++){ offs[e] = s; s += counts[e]; }
  }
}

// fast path: scatter with local prefix + pos record
__global__ void scatter2_k(const int* __restrict__ topk_e, const float* __restrict__ topk_w,
                           const int* __restrict__ counts, int* __restrict__ cursor,
                           int* __restrict__ row_tok, float* __restrict__ row_w,
                           int* __restrict__ pos){
  int t = blockIdx.x*blockDim.x + threadIdx.x;
  if (t >= T_TOK) return;
  int offs[NE]; int s = 0;
  #pragma unroll
  for (int e=0;e<NE;e++){ offs[e] = s; s += counts[e]; }
  #pragma unroll
  for (int k=0;k<2;k++){
    int e = topk_e[t*2+k];
    int p = atomicAdd(&cursor[e], 1);
    int flat = offs[e] + p;
    row_tok[flat] = t;
    row_w[flat]   = topk_w[t*2+k];
    pos[t*2+k]    = flat;
  }
}

// fallback scatter
__global__ void scatter_k(const int* __restrict__ topk_e, const float* __restrict__ topk_w,
                          const int* __restrict__ offs, int* __restrict__ cursor,
                          int* __restrict__ row_tok, float* __restrict__ row_w){
  int t = blockIdx.x*blockDim.x + threadIdx.x;
  if (t >= T_TOK) return;
  #pragma unroll
  for (int k=0;k<2;k++){
    int e = topk_e[t*2+k];
    int p = atomicAdd(&cursor[e], 1);
    int flat = offs[e] + p;
    row_tok[flat] = t;
    row_w[flat]   = topk_w[t*2+k];
  }
}

// ---------------- combine: out[t] = obuf[pos0] + obuf[pos1] ----------------

__global__ __launch_bounds__(256) void combine_k(
    const unsigned short* __restrict__ obuf, const int* __restrict__ pos,
    float* __restrict__ out)
{
  const int t = blockIdx.x;
  const int p0 = pos[t*2], p1 = pos[t*2+1];
  const unsigned short* r0 = obuf + (size_t)p0*DIM;
  const unsigned short* r1 = obuf + (size_t)p1*DIM;
  float* o = out + (size_t)t*DIM;
  const int d = threadIdx.x*4;
  const ushort4 a = *(const ushort4*)(r0 + d);
  const ushort4 b = *(const ushort4*)(r1 + d);
  float4 v;
  v.x = bf2f(a.x) + bf2f(b.x);
  v.y = bf2f(a.y) + bf2f(b.y);
  v.z = bf2f(a.z) + bf2f(b.z);
  v.w = bf2f(a.w) + bf2f(b.w);
  *(float4*)(o + d) = v;
}

// ============ FAST GEMMs ============
// Resource law (r2-r12): <=128 regs/wave, <=80KB LDS, >=2 blocks/CU, >=1024 blocks.
// M/R=2.0 per step. Swizzles verified 0-conflict (r6/r7).

// GEMM1 (round-6 proven): 128x128x2 tile, 8 waves (2x4), BK=32, ring-3, vmcnt(3)
__global__ __launch_bounds__(512,2) void gemm1_p(
    const unsigned short* __restrict__ xbf,
    const unsigned short* __restrict__ w1t, const unsigned short* __restrict__ w3t,
    unsigned short* __restrict__ hbuf,
    const int* __restrict__ row_tok,
    const int* __restrict__ counts, const int* __restrict__ offs)
{
  __shared__ unsigned short As [3][128*32];
  __shared__ unsigned short B1s[3][128*32];
  __shared__ unsigned short B3s[3][128*32];   // 72 KB total

  const int i   = blockIdx.y*64 + blockIdx.x;
  const int lid = (i & 7)*1408 + (i >> 3);
  const int e   = lid / 1408;
  const int rem = lid - e*1408;
  const int h0  = (rem >> 6) * 128;
  const int rb  = rem & 63;

  const int cnt = counts[e];
  const int row0 = rb * 128;
  if (row0 >= cnt) return;
  const int nv   = min(128, cnt - row0);
  const int base = offs[e] + row0;
  const int NK   = DIM/32;

  const int t = threadIdx.x;
  const int r_loc = t >> 2, sct = t & 3;
  const int csw = (sct ^ ((r_loc >> 1) & 3)) * 8;
  const int tok = row_tok[base + min(r_loc, nv-1)];
  const unsigned short* aS  = xbf + (size_t)tok*DIM + csw;
  const unsigned short* b1S = w1t + ((size_t)(e*NH + h0) + r_loc)*DIM + csw;
  const unsigned short* b3S = w3t + ((size_t)(e*NH + h0) + r_loc)*DIM + csw;
  const int lo = t*16;

  const int wid = t >> 6, l = t & 63;
  const int wr = wid >> 2, wc = wid & 3;
  const int lr = l & 15,  lk = l >> 4;
  const int rc = (lk ^ ((lr >> 1) & 3)) * 8;

  f32x4 acc1[4][2], acc3[4][2];
  #pragma unroll
  for (int m=0;m<4;m++)
    #pragma unroll
    for (int n=0;n<2;n++){ acc1[m][n] = (f32x4)0.f; acc3[m][n] = (f32x4)0.f; }

  GLL(aS,    (char*)As[0]+lo); GLL(b1S,    (char*)B1s[0]+lo); GLL(b3S,    (char*)B3s[0]+lo);
  GLL(aS+32, (char*)As[1]+lo); GLL(b1S+32, (char*)B1s[1]+lo); GLL(b3S+32, (char*)B3s[1]+lo);

  for (int kt=0; kt<NK; ++kt){
    if (kt < NK-1) asm volatile("s_waitcnt vmcnt(3)" ::: "memory");
    else           asm volatile("s_waitcnt vmcnt(0)" ::: "memory");
    __builtin_amdgcn_s_barrier();

    if (kt+2 < NK){
      const int kA = (kt+2)*32;
      char* ad  = (char*)As [(kt+2)%3];
      char* b1d = (char*)B1s[(kt+2)%3];
      char* b3d = (char*)B3s[(kt+2)%3];
      GLL(aS+kA, ad+lo); GLL(b1S+kA, b1d+lo); GLL(b3S+kA, b3d+lo);
    }

    const unsigned short* Ab  = As [kt%3];
    const unsigned short* B1b = B1s[kt%3];
    const unsigned short* B3b = B3s[kt%3];

    bf16x8 a[4], b1[2], b3[2];
    #pragma unroll
    for (int m=0;m<4;m++) a[m] = *(const bf16x8*)&Ab[(wr*64 + m*16 + lr)*32 + rc];
    #pragma unroll
    for (int n=0;n<2;n++){
      b1[n] = *(const bf16x8*)&B1b[(wc*32 + n*16 + lr)*32 + rc];
      b3[n] = *(const bf16x8*)&B3b[(wc*32 + n*16 + lr)*32 + rc];
    }
    __builtin_amdgcn_s_setprio(1);
    #pragma unroll
    for (int m=0;m<4;m++)
      #pragma unroll
      for (int n=0;n<2;n++){
        acc1[m][n] = MFMA16(a[m], b1[n], acc1[m][n]);
        acc3[m][n] = MFMA16(a[m], b3[n], acc3[m][n]);
      }
    __builtin_amdgcn_s_setprio(0);
  }

  #pragma unroll
  for (int m=0;m<4;m++){
    #pragma unroll
    for (int i2=0;i2<4;i2++){
      const int r = wr*64 + m*16 + lk*4 + i2;
      if (r < nv){
        const size_t rowbase = (size_t)(base + r) * NH;
        #pragma unroll
        for (int n=0;n<2;n++){
          float z  = acc1[m][n][i2];
          float p3 = acc3[m][n][i2];
          float hv = (z / (1.f + __expf(-z))) * p3;
          hbuf[rowbase + h0 + wc*32 + n*16 + lr] = f2bf(hv);
        }
      }
    }
  }
}

// GEMM2 (r12 core, non-atomic bf16 obuf epilogue): 128x128 tile, 4 waves (2x2),
// acc[4][4]=64 AGPR, M/R=2.0, BK=32 ring-3 (48 KB -> 3 blocks/CU), vmcnt(4).
__global__ __launch_bounds__(256,3) void gemm2_o(
    const unsigned short* __restrict__ hbuf,
    const unsigned short* __restrict__ w2t,
    unsigned short* __restrict__ obuf,
    const float* __restrict__ row_w,
    const int* __restrict__ counts, const int* __restrict__ offs)
{
  __shared__ unsigned short As[3][128*32];   // 24 KB
  __shared__ unsigned short Bs[3][128*32];   // 24 KB -> 48 KB

  const int i   = blockIdx.y*64 + blockIdx.x;     // grid (64, NE*8)
  const int lid = (i & 7)*512 + (i >> 3);
  const int e   = lid >> 9;
  const int rem = lid & 511;
  const int d0  = (rem >> 6) * 128;
  const int rb  = rem & 63;

  const int cnt = counts[e];
  const int row0 = rb * 128;
  if (row0 >= cnt) return;
  const int nv   = min(128, cnt - row0);
  const int base = offs[e] + row0;
  const int NK   = NH/32;                         // 88

  const int t = threadIdx.x;                      // 256 threads
  const int r_loc = t >> 2, sct = t & 3;
  const int csw = (sct ^ ((r_loc >> 1) & 3)) * 8;
  const unsigned short* aS0 = hbuf + (size_t)(base + min(r_loc,      nv-1))*NH + csw;
  const unsigned short* aS1 = hbuf + (size_t)(base + min(r_loc + 64, nv-1))*NH + csw;
  const unsigned short* bS0 = w2t + ((size_t)(e*DIM + d0) + r_loc)*NH + csw;
  const unsigned short* bS1 = bS0 + (size_t)64*NH;
  const int lo0 = t*16, lo1 = 4096 + t*16;

  const int wid = t >> 6, l = t & 63;
  const int wr = wid >> 1, wc = wid & 1;          // 2x2 waves, 64x64 out each
  const int lr = l & 15,  lk = l >> 4;
  const int rc = (lk ^ ((lr >> 1) & 3)) * 8;

  f32x4 acc[4][4];                                // 64 AGPR
  #pragma unroll
  for (int m=0;m<4;m++)
    #pragma unroll
    for (int n=0;n<4;n++) acc[m][n] = (f32x4)0.f;

  GLL(aS0,    (char*)As[0]+lo0); GLL(aS1,    (char*)As[0]+lo1);
  GLL(bS0,    (char*)Bs[0]+lo0); GLL(bS1,    (char*)Bs[0]+lo1);
  GLL(aS0+32, (char*)As[1]+lo0); GLL(aS1+32, (char*)As[1]+lo1);
  GLL(bS0+32, (char*)Bs[1]+lo0); GLL(bS1+32, (char*)Bs[1]+lo1);

  for (int kt=0; kt<NK; ++kt){
    if (kt < NK-1) asm volatile("s_waitcnt vmcnt(4)" ::: "memory");
    else           asm volatile("s_waitcnt vmcnt(0)" ::: "memory");
    __builtin_amdgcn_s_barrier();

    if (kt+2 < NK){
      const int kA = (kt+2)*32;
      char* ad = (char*)As[(kt+2)%3];
      char* bd = (char*)Bs[(kt+2)%3];
      GLL(aS0+kA, ad+lo0); GLL(aS1+kA, ad+lo1);
      GLL(bS0+kA, bd+lo0); GLL(bS1+kA, bd+lo1);
    }

    const unsigned short* Ab = As[kt%3];
    const unsigned short* Bb = Bs[kt%3];

    bf16x8 a[4], b[4];
    #pragma unroll
    for (int m=0;m<4;m++) a[m] = *(const bf16x8*)&Ab[(wr*64 + m*16 + lr)*32 + rc];
    #pragma unroll
    for (int n=0;n<4;n++)  b[n] = *(const bf16x8*)&Bb[(wc*64 + n*16 + lr)*32 + rc];
    __builtin_amdgcn_s_setprio(1);
    #pragma unroll
    for (int m=0;m<4;m++)
      #pragma unroll
      for (int n=0;n<4;n++)
        acc[m][n] = MFMA16(a[m], b[n], acc[m][n]);
    __builtin_amdgcn_s_setprio(0);
  }

  #pragma unroll
  for (int m=0;m<4;m++){
    #pragma unroll
    for (int i2=0;i2<4;i2++){
      const int r = wr*64 + m*16 + lk*4 + i2;
      if (r < nv){
        const int flat = base + r;
        const float wgt = row_w[flat];
        unsigned short* orow = obuf + (size_t)flat * DIM + d0 + wc*64;
        #pragma unroll
        for (int n=0;n<4;n++)
          orow[n*16 + lr] = f2bf(acc[m][n][i2] * wgt);
      }
    }
  }
}

// ============ SLOW FALLBACK (f32 weights, small ws) ============

__global__ __launch_bounds__(256) void gemm1_k(
    const unsigned short* __restrict__ xbf,
    const float* __restrict__ w1, const float* __restrict__ w3,
    unsigned short* __restrict__ hbuf,
    const int* __restrict__ row_tok,
    const int* __restrict__ counts, const int* __restrict__ offs)
{
  __shared__ unsigned short Al [128*32];
  __shared__ unsigned short B1l[128*32];
  __shared__ unsigned short B3l[128*32];
  const int e   = blockIdx.y >> 6;
  const int rb  = blockIdx.y & 63;
  const int cnt = counts[e];
  const int row0 = rb * 128;
  if (row0 >= cnt) return;
  const int nv   = min(128, cnt - row0);
  const int base = offs[e] + row0;
  const int h0   = blockIdx.x * 128;
  const int t  = threadIdx.x;
  const int ar0 = t >> 2;
  const int ac  = t & 3;
  const int tok0 = row_tok[base + min(ar0,      nv-1)];
  const int tok1 = row_tok[base + min(ar0 + 64, nv-1)];
  const size_t asrc0 = (size_t)tok0 * DIM + ac*8;
  const size_t asrc1 = (size_t)tok1 * DIM + ac*8;
  const int dg = t >> 5;
  const int hq = t & 31;
  const float* w1p = w1 + (size_t)e * DIM * NH + (size_t)(h0 + hq*4);
  const float* w3p = w3 + (size_t)e * DIM * NH + (size_t)(h0 + hq*4);
  const int wid = t >> 6, l = t & 63;
  const int wr = wid >> 1, wc = wid & 1;
  const int lr = l & 15,  lk = l >> 4;
  f32x4 acc1[4][4], acc3[4][4];
  #pragma unroll
  for (int m=0;m<4;m++)
    #pragma unroll
    for (int n=0;n<4;n++){ acc1[m][n] = (f32x4)0.f; acc3[m][n] = (f32x4)0.f; }
  for (int kk=0; kk<DIM/32; ++kk){
    const int k0 = kk*32;
    __syncthreads();
    *(uint4*)&Al[ar0*32 + ac*8]      = *(const uint4*)(xbf + asrc0 + k0);
    *(uint4*)&Al[(ar0+64)*32 + ac*8] = *(const uint4*)(xbf + asrc1 + k0);
    {
      const float4 f0 = *(const float4*)(w1p + (size_t)(k0 + dg*4 + 0)*NH);
      const float4 f1 = *(const float4*)(w1p + (size_t)(k0 + dg*4 + 1)*NH);
      const float4 f2 = *(const float4*)(w1p + (size_t)(k0 + dg*4 + 2)*NH);
      const float4 f3 = *(const float4*)(w1p + (size_t)(k0 + dg*4 + 3)*NH);
      const float* p0=(const float*)&f0; const float* p1=(const float*)&f1;
      const float* p2=(const float*)&f2; const float* p3=(const float*)&f3;
      #pragma unroll
      for (int j=0;j<4;j++){
        ushort4 pk = make_ushort4(f2bf(p0[j]), f2bf(p1[j]), f2bf(p2[j]), f2bf(p3[j]));
        *(ushort4*)&B1l[(hq*4+j)*32 + dg*4] = pk;
      }
      const float4 g0 = *(const float4*)(w3p + (size_t)(k0 + dg*4 + 0)*NH);
      const float4 g1 = *(const float4*)(w3p + (size_t)(k0 + dg*4 + 1)*NH);
      const float4 g2 = *(const float4*)(w3p + (size_t)(k0 + dg*4 + 2)*NH);
      const float4 g3 = *(const float4*)(w3p + (size_t)(k0 + dg*4 + 3)*NH);
      const float* q0=(const float*)&g0; const float* q1=(const float*)&g1;
      const float* q2=(const float*)&g2; const float* q3=(const float*)&g3;
      #pragma unroll
      for (int j=0;j<4;j++){
        ushort4 pk = make_ushort4(f2bf(q0[j]), f2bf(q1[j]), f2bf(q2[j]), f2bf(q3[j]));
        *(ushort4*)&B3l[(hq*4+j)*32 + dg*4] = pk;
      }
    }
    __syncthreads();
    bf16x8 a[4], b1[4], b3[4];
    #pragma unroll
    for (int m=0;m<4;m++) a[m] = *(const bf16x8*)&Al[(wr*64 + m*16 + lr)*32 + lk*8];
    #pragma unroll
    for (int n=0;n<4;n++){
      b1[n] = *(const bf16x8*)&B1l[(wc*64 + n*16 + lr)*32 + lk*8];
      b3[n] = *(const bf16x8*)&B3l[(wc*64 + n*16 + lr)*32 + lk*8];
    }
    #pragma unroll
    for (int m=0;m<4;m++)
      #pragma unroll
      for (int n=0;n<4;n++){
        acc1[m][n] = MFMA16(a[m], b1[n], acc1[m][n]);
        acc3[m][n] = MFMA16(a[m], b3[n], acc3[m][n]);
      }
  }
  #pragma unroll
  for (int m=0;m<4;m++){
    #pragma unroll
    for (int i=0;i<4;i++){
      const int r = wr*64 + m*16 + lk*4 + i;
      if (r < nv){
        const size_t rowbase = (size_t)(base + r) * NH;
        #pragma unroll
        for (int n=0;n<4;n++){
          float z  = acc1[m][n][i];
          float p3 = acc3[m][n][i];
          float hv = (z / (1.f + __expf(-z))) * p3;
          hbuf[rowbase + h0 + wc*64 + n*16 + lr] = f2bf(hv);
        }
      }
    }
  }
}

__global__ __launch_bounds__(256) void gemm2_k(
    const unsigned short* __restrict__ hbuf,
    const float* __restrict__ w2,
    float* __restrict__ out,
    const int* __restrict__ row_tok, const float* __restrict__ row_w,
    const int* __restrict__ counts, const int* __restrict__ offs)
{
  __shared__ unsigned short Al[128*32];
  __shared__ unsigned short Bl[128*32];
  const int e   = blockIdx.y >> 6;
  const int rb  = blockIdx.y & 63;
  const int cnt = counts[e];
  const int row0 = rb * 128;
  if (row0 >= cnt) return;
  const int nv   = min(128, cnt - row0);
  const int base = offs[e] + row0;
  const int d0   = blockIdx.x * 128;
  const int t  = threadIdx.x;
  const int ar0 = t >> 2;
  const int ac  = t & 3;
  const size_t asrc0 = (size_t)(base + min(ar0,      nv-1)) * NH + ac*8;
  const size_t asrc1 = (size_t)(base + min(ar0 + 64, nv-1)) * NH + ac*8;
  const int dg = t >> 5;
  const int hq = t & 31;
  const float* w2p = w2 + (size_t)e * NH * DIM + (size_t)(d0 + hq*4);
  const int wid = t >> 6, l = t & 63;
  const int wr = wid >> 1, wc = wid & 1;
  const int lr = l & 15,  lk = l >> 4;
  f32x4 acc[4][4];
  #pragma unroll
  for (int m=0;m<4;m++)
    #pragma unroll
    for (int n=0;n<4;n++) acc[m][n] = (f32x4)0.f;
  for (int kk=0; kk<NH/32; ++kk){
    const int k0 = kk*32;
    __syncthreads();
    *(uint4*)&Al[ar0*32 + ac*8]      = *(const uint4*)(hbuf + asrc0 + k0);
    *(uint4*)&Al[(ar0+64)*32 + ac*8] = *(const uint4*)(hbuf + asrc1 + k0);
    {
      const float4 f0 = *(const float4*)(w2p + (size_t)(k0 + dg*4 + 0)*DIM);
      const float4 f1 = *(const float4*)(w2p + (size_t)(k0 + dg*4 + 1)*DIM);
      const float4 f2 = *(const float4*)(w2p + (size_t)(k0 + dg*4 + 2)*DIM);
      const float4 f3 = *(const float4*)(w2p + (size_t)(k0 + dg*4 + 3)*DIM);
      const float* p0=(const float*)&f0; const float* p1=(const float*)&f1;
      const float* p2=(const float*)&f2; const float* p3=(const float*)&f3;
      #pragma unroll
      for (int j=0;j<4;j++){
        ushort4 pk = make_ushort4(f2bf(p0[j]), f2bf(p1[j]), f2bf(p2[j]), f2bf(p3[j]));
        *(ushort4*)&Bl[(hq*4+j)*32 + dg*4] = pk;
      }
    }
    __syncthreads();
    bf16x8 a[4], b[4];
    #pragma unroll
    for (int m=0;m<4;m++) a[m] = *(const bf16x8*)&Al[(wr*64 + m*16 + lr)*32 + lk*8];
    #pragma unroll
    for (int n=0;n<4;n++)  b[n] = *(const bf16x8*)&Bl[(wc*64 + n*16 + lr)*32 + lk*8];
    #pragma unroll
    for (int m=0;m<4;m++)
      #pragma unroll
      for (int n=0;n<4;n++)
        acc[m][n] = MFMA16(a[m], b[n], acc[m][n]);
  }
  #pragma unroll
  for (int m=0;m<4;m++){
    #pragma unroll
    for (int i=0;i<4;i++){
      const int r = wr*64 + m*16 + lk*4 + i;
      if (r < nv){
        const int flat = base + r;
        const int tok  = row_tok[flat];
        const float wgt = row_w[flat];
        float* orow = out + (size_t)tok * DIM + d0 + wc*64;
        #pragma unroll
        for (int n=0;n<4;n++)
          atomicAdd(&orow[n*16 + lr], acc[m][n][i] * wgt);
      }
    }
  }
}

// ---------------- launch ----------------

extern "C" void kernel_launch(void* const* d_in, const int* in_sizes, int n_in,
                              void* d_out, int out_size, void* d_ws, size_t ws_size,
                              hipStream_t stream) {
  (void)in_sizes; (void)n_in; (void)out_size;
  const float* x   = (const float*)d_in[0];
  const float* rw  = (const float*)d_in[1];
  const float* w1  = (const float*)d_in[2];
  const float* w2  = (const float*)d_in[3];
  const float* w3  = (const float*)d_in[4];
  float* out = (float*)d_out;
  char* ws = (char*)d_ws;

  const size_t SZ_XBF  = (size_t)T_TOK*DIM*2;
  const size_t SZ_HBUF = (size_t)NROWS*NH*2;
  const size_t SZ_WT   = (size_t)NE*NH*DIM*2;
  const size_t SZ_OBUF = (size_t)NROWS*DIM*2;      // 33.5 MB <= SZ_WT (overlay ok)
  const size_t SZ_SMALL = (size_t)NROWS*4*2 + (size_t)T_TOK*2*4*3 + 3*64*4 + 4096;
  const size_t NEED_FAST = SZ_XBF + SZ_HBUF + 2*SZ_WT + SZ_SMALL;

  if (ws_size >= NEED_FAST) {
    size_t off = 0;
    unsigned short* xbf  = (unsigned short*)(ws + off); off += SZ_XBF;
    unsigned short* hbuf = (unsigned short*)(ws + off); off += SZ_HBUF;
    unsigned short* w1t  = (unsigned short*)(ws + off); off += SZ_WT;
    unsigned short* w3t  = (unsigned short*)(ws + off); off += SZ_WT;
    unsigned short* obuf = w1t;   // overlay: w1t dead after gemm1 (33.5 <= 46.1 MB)
    unsigned short* w2t  = w3t;   // overlay: w3t dead after gemm1
    int*   row_tok = (int*)  (ws + off); off += NROWS*4;
    float* row_w   = (float*)(ws + off); off += NROWS*4;
    int*   topk_e  = (int*)  (ws + off); off += T_TOK*2*4;
    float* topk_w  = (float*)(ws + off); off += T_TOK*2*4;
    int*   pos     = (int*)  (ws + off); off += T_TOK*2*4;
    int*   counts  = (int*)  (ws + off); off += 64;
    int*   offs    = (int*)  (ws + off); off += 64;
    int*   cursor  = (int*)  (ws + off); off += 64;

    init2_k   <<<1, 64, 0, stream>>>(counts, cursor);
    router_k  <<<T_TOK, 64, 0, stream>>>(x, rw, xbf, topk_e, topk_w, counts);
    prefix_k  <<<1, 64, 0, stream>>>(counts, offs);
    scatter2_k<<<(T_TOK+255)/256, 256, 0, stream>>>(topk_e, topk_w, counts, cursor, row_tok, row_w, pos);
    transpA_k <<<dim3(704, 16), 256, 0, stream>>>(w1, w3, w2, w1t, w3t, w2t, 0);
    gemm1_p   <<<dim3(64, 176), 512, 0, stream>>>(xbf, w1t, w3t, hbuf, row_tok, counts, offs);
    transpA_k <<<dim3(704, 8), 256, 0, stream>>>(w1, w3, w2, w1t, w3t, w2t, 16);
    gemm2_o   <<<dim3(64, NE*8), 256, 0, stream>>>(hbuf, w2t, obuf, row_w, counts, offs);
    combine_k <<<T_TOK, 256, 0, stream>>>(obuf, pos, out);
  } else {
    size_t off = 0;
    unsigned short* xbf  = (unsigned short*)(ws + off); off += SZ_XBF;
    unsigned short* hbuf = (unsigned short*)(ws + off); off += SZ_HBUF;
    int*   row_tok = (int*)  (ws + off); off += NROWS*4;
    float* row_w   = (float*)(ws + off); off += NROWS*4;
    int*   topk_e  = (int*)  (ws + off); off += T_TOK*2*4;
    float* topk_w  = (float*)(ws + off); off += T_TOK*2*4;
    int*   counts  = (int*)  (ws + off); off += 64;
    int*   offs    = (int*)  (ws + off); off += 64;
    int*   cursor  = (int*)  (ws + off); off += 64;

    zero_init_k<<<2048, 256, 0, stream>>>((float4*)out, counts, cursor);
    router_k   <<<T_TOK, 64, 0, stream>>>(x, rw, xbf, topk_e, topk_w, counts);
    prefix_k   <<<1, 64, 0, stream>>>(counts, offs);
    scatter_k  <<<(T_TOK+255)/256, 256, 0, stream>>>(topk_e, topk_w, offs, cursor, row_tok, row_w);
    gemm1_k    <<<dim3(NH/128, NE*64), 256, 0, stream>>>(xbf, w1, w3, hbuf, row_tok, counts, offs);
    gemm2_k    <<<dim3(DIM/128, NE*64), 256, 0, stream>>>(hbuf, w2, out, row_tok, row_w, counts, offs);
  }
}